// Round 8
// baseline (7817.827 us; speedup 1.0000x reference)
//
#include <hip/hip_runtime.h>
#include <math.h>
#include <stdint.h>

// Problem constants (T=1024, B=64, D=512, H=512), fp32 everywhere.
#define TT      1024
#define BATCH   64
#define HH      512
#define NG      8      // batch groups (8 rows each)
#define WPG     32     // workgroups per group (H split 512/16)
#define BSL     8      // batch rows per group
#define HSL     16     // output rows per workgroup
#define NTH     512    // threads per block (8 waves)

// ---- LDS layout (floats) ----
// Weights packed in wave-read order (R6-proven): [mat(3)][jj(2)][u(4)] blocks
// of 1024 floats, inner = [ks(32)][jp(8)]·float4.  Per-wave weight read =
// contiguous 512B, 2-way bb-broadcast -> conflict-free.
#define WBLK(m, jj, u)  ((((m) * 2 + (jj)) * 4 + (u)) << 10)
#define WLDS    (24 * 1024)             // 24576 floats
// Reduce scratch (R6-proven): 129 rows x 17 stride.
#define SCR     WLDS
#define SCRS    17
#define LDS_FL  (SCR + 129 * SCRS)      // 26769 floats
#define LDS_BYTES (LDS_FL * 4)          // 107076 B  (>80KB on purpose: pins
                                        //  exactly 1 block/CU for the barrier)

// ---- LLC-coherent helpers (relaxed SYSTEM scope => sc0|sc1 loads/stores,
// complete at the Infinity Cache; COMPILER-TRACKED so waitcnts cover every
// use incl. RA-inserted spills — R7 post-mortem: raw-asm loads are not) ----
__device__ __forceinline__ float2 sys_ld2(const float* p) {
    unsigned long long v = __hip_atomic_load((const unsigned long long*)p, __ATOMIC_RELAXED,
                                             __HIP_MEMORY_SCOPE_SYSTEM);
    union { unsigned long long u; float2 f; } cv; cv.u = v; return cv.f;
}
__device__ __forceinline__ void sys_st(float* p, float v) {
    __hip_atomic_store(p, v, __ATOMIC_RELAXED, __HIP_MEMORY_SCOPE_SYSTEM);
}
__device__ __forceinline__ void wait_vm0() {
    asm volatile("s_waitcnt vmcnt(0)" ::: "memory");
}
__device__ __forceinline__ void dot4(float4 w, float4 x, float& a) {
    a = fmaf(w.x, x.x, a); a = fmaf(w.y, x.y, a);
    a = fmaf(w.z, x.z, a); a = fmaf(w.w, x.w, a);
}

// ============================================================================
// Kernel 1: Z0 = Xt @ Wih0^T + bih0, written into `out` (aliasing safe:
// out[t] is consumed as Z0 at phase t-1 (prefetch) and overwritten at t+1;
// all post-overwrite readers use LLC-scope loads).
// ============================================================================
__global__ void __launch_bounds__(256)
z0_gemm(const float* __restrict__ X, const float* __restrict__ W,
        const float* __restrict__ bih, float* __restrict__ Z)
{
    __shared__ float As[32][68];
    __shared__ float Bs[32][68];
    const int tid = threadIdx.x;
    const int tx  = tid & 15, ty = tid >> 4;
    const int n0  = (blockIdx.x & 7) * 64;
    const int m0  = (blockIdx.x >> 3) * 64;
    const int lm  = tid >> 3;
    const int lk  = (tid & 7) * 4;

    float4 bb;
    bb.x = bih[n0 + tx * 4 + 0]; bb.y = bih[n0 + tx * 4 + 1];
    bb.z = bih[n0 + tx * 4 + 2]; bb.w = bih[n0 + tx * 4 + 3];

    float acc[4][4];
    #pragma unroll
    for (int i = 0; i < 4; ++i)
        #pragma unroll
        for (int j = 0; j < 4; ++j) acc[i][j] = 0.f;

    for (int k0 = 0; k0 < 512; k0 += 32) {
        float4 a0 = *(const float4*)(X + (size_t)(m0 + lm) * 512 + k0 + lk);
        float4 a1 = *(const float4*)(X + (size_t)(m0 + lm + 32) * 512 + k0 + lk);
        float4 b0 = *(const float4*)(W + (size_t)(n0 + lm) * 512 + k0 + lk);
        float4 b1 = *(const float4*)(W + (size_t)(n0 + lm + 32) * 512 + k0 + lk);
        __syncthreads();
        As[lk + 0][lm] = a0.x; As[lk + 1][lm] = a0.y;
        As[lk + 2][lm] = a0.z; As[lk + 3][lm] = a0.w;
        As[lk + 0][lm + 32] = a1.x; As[lk + 1][lm + 32] = a1.y;
        As[lk + 2][lm + 32] = a1.z; As[lk + 3][lm + 32] = a1.w;
        Bs[lk + 0][lm] = b0.x; Bs[lk + 1][lm] = b0.y;
        Bs[lk + 2][lm] = b0.z; Bs[lk + 3][lm] = b0.w;
        Bs[lk + 0][lm + 32] = b1.x; Bs[lk + 1][lm + 32] = b1.y;
        Bs[lk + 2][lm + 32] = b1.z; Bs[lk + 3][lm + 32] = b1.w;
        __syncthreads();
        #pragma unroll
        for (int kk = 0; kk < 32; ++kk) {
            float4 av = *(const float4*)(&As[kk][ty * 4]);
            float4 bv = *(const float4*)(&Bs[kk][tx * 4]);
            acc[0][0] = fmaf(av.x, bv.x, acc[0][0]); acc[0][1] = fmaf(av.x, bv.y, acc[0][1]);
            acc[0][2] = fmaf(av.x, bv.z, acc[0][2]); acc[0][3] = fmaf(av.x, bv.w, acc[0][3]);
            acc[1][0] = fmaf(av.y, bv.x, acc[1][0]); acc[1][1] = fmaf(av.y, bv.y, acc[1][1]);
            acc[1][2] = fmaf(av.y, bv.z, acc[1][2]); acc[1][3] = fmaf(av.y, bv.w, acc[1][3]);
            acc[2][0] = fmaf(av.z, bv.x, acc[2][0]); acc[2][1] = fmaf(av.z, bv.y, acc[2][1]);
            acc[2][2] = fmaf(av.z, bv.z, acc[2][2]); acc[2][3] = fmaf(av.z, bv.w, acc[2][3]);
            acc[3][0] = fmaf(av.w, bv.x, acc[3][0]); acc[3][1] = fmaf(av.w, bv.y, acc[3][1]);
            acc[3][2] = fmaf(av.w, bv.z, acc[3][2]); acc[3][3] = fmaf(av.w, bv.w, acc[3][3]);
        }
    }
    #pragma unroll
    for (int i = 0; i < 4; ++i) {
        float4 r;
        r.x = acc[i][0] + bb.x; r.y = acc[i][1] + bb.y;
        r.z = acc[i][2] + bb.z; r.w = acc[i][3] + bb.w;
        *(float4*)(Z + (size_t)(m0 + ty * 4 + i) * 512 + n0 + tx * 4) = r;
    }
}

// ============================================================================
// Kernel 2: persistent 3-matmul recurrence.  Activations direct from LLC to
// registers via COMPILER-TRACKED sys_ld2 (no LDS staging, no S1 barrier);
// weights in packed LDS; reduce/tail/counter-barrier identical to passed-R6.
// ============================================================================
__global__ void __launch_bounds__(NTH, 2)
elman_persistent(const float* __restrict__ Whh0, const float* __restrict__ bhh0,
                 const float* __restrict__ Wih1, const float* __restrict__ bih1,
                 const float* __restrict__ Whh1, const float* __restrict__ bhh1,
                 float* __restrict__ out,   // [T][B][H]: Z0 on entry, h1 history on exit
                 float* h0buf,              // [2][B][H] double-buffered h0 (ws, zeroed)
                 unsigned* cnt)             // NG counters, 256B stride (ws, zeroed)
{
    extern __shared__ float lds[];
    const int tid = threadIdx.x;
    const int g   = blockIdx.x & 7;     // batch group
    const int w   = blockIdx.x >> 3;    // H-slice index
    const int jg0 = w * HSL;
    const int bg0 = g * BSL;

    // decomposition: tid = ks(5b)<<4 | bb(1b)<<3 | jp(3b); j_t=2, b_t=4
    const int jp   = tid & 7;
    const int bb4  = ((tid >> 3) & 1) * 4;
    const int ks   = tid >> 4;          // 0..31
    const int kb   = ks * 4;
    const int wofs = ks * 32 + jp * 4;  // packed-weight lane offset (floats)
    const int lane = tid & 63;
    const int wv   = tid >> 6;

    // ---- one-time: stage 3 weight mats into PACKED LDS layout ----
    {
        const float* const Ws[3] = {Whh0, Wih1, Whh1};
        for (int f = tid; f < 48 * 128; f += NTH) {
            const int jrow = f >> 7, k4 = f & 127;
            const int mat = jrow >> 4, r = jrow & 15;
            const int jp_ = r >> 1, jj_ = r & 1;
            const int u_ = k4 >> 5, ks_ = k4 & 31;
            float4 v = ((const float4*)(Ws[mat] + (size_t)(jg0 + r) * HH))[k4];
            *(float4*)(lds + WBLK(mat, jj_, u_) + ks_ * 32 + jp_ * 4) = v;
        }
    }
    float bias = 0.f;
    if (tid < 256) {
        const int l = tid >> 7, jx = jg0 + (tid & 15);
        bias = l ? (bih1[jx] + bhh1[jx]) : bhh0[jx];
    }
    // prologue: z0 for phase 0 (plain cached; first touch, data unchanged
    // since z0_gemm whose dirty L2 is flushed at its dispatch end)
    float z0cur = 0.f;
    if (tid < 128)
        z0cur = out[(size_t)(bg0 + (tid >> 4)) * HH + jg0 + (tid & 15)];
    __syncthreads();

    unsigned* mycnt = cnt + g * 64;      // 256B stride between group counters
    unsigned target = 0;
    bool     dead   = false;             // barrier watchdog

    for (int p = 0; p <= TT; ++p) {
        const bool doL0  = (p < TT);
        const bool doL1  = (p >= 1);
        const bool hasH1 = (p >= 2);
        const int  cur   = p & 1;

        // 1. issue all LLC loads straight into registers (compiler-tracked;
        //    h1 latency hides under the h0-pass via normal waitcnt scheduling)
        float4 h0r[4][4];
        {
            const float* b0 = h0buf + (size_t)((p + 1) & 1) * (BATCH * HH)
                            + (size_t)(bg0 + bb4) * HH + kb;
            #pragma unroll
            for (int bi = 0; bi < 4; ++bi) {
                const float* pp = b0 + bi * HH;
                #pragma unroll
                for (int u = 0; u < 4; ++u) {
                    float2 lo = sys_ld2(pp + u * 128);
                    float2 hi = sys_ld2(pp + u * 128 + 2);
                    h0r[bi][u] = make_float4(lo.x, lo.y, hi.x, hi.y);
                }
            }
        }
        float4 h1r[4][4];
        if (hasH1) {
            const float* b1 = out + ((size_t)(p - 2) * BATCH + bg0 + bb4) * HH + kb;
            #pragma unroll
            for (int bi = 0; bi < 4; ++bi) {
                const float* pp = b1 + bi * HH;
                #pragma unroll
                for (int u = 0; u < 4; ++u) {
                    float2 lo = sys_ld2(pp + u * 128);
                    float2 hi = sys_ld2(pp + u * 128 + 2);
                    h1r[bi][u] = make_float4(lo.x, lo.y, hi.x, hi.y);
                }
            }
        }
        float z0n = 0.f;   // out[p+1] untouched until phase p+2 -> plain load safe
        if (p + 1 < TT && tid < 128)
            z0n = out[((size_t)(p + 1) * BATCH + bg0 + (tid >> 4)) * HH + jg0 + (tid & 15)];

        float acc0[2][4], acc1[2][4];
        #pragma unroll
        for (int jj = 0; jj < 2; ++jj)
            #pragma unroll
            for (int bi = 0; bi < 4; ++bi) { acc0[jj][bi] = 0.f; acc1[jj][bi] = 0.f; }

        // 2. h0-pass: Whh0 -> acc0, Wih1 -> acc1 (unconditional; edge-phase
        //    garbage is discarded by the guarded tail stores)
        #pragma unroll
        for (int u = 0; u < 4; ++u) {
            float4 wa0 = *(const float4*)(lds + WBLK(0, 0, u) + wofs);
            float4 wa1 = *(const float4*)(lds + WBLK(0, 1, u) + wofs);
            float4 wb0 = *(const float4*)(lds + WBLK(1, 0, u) + wofs);
            float4 wb1 = *(const float4*)(lds + WBLK(1, 1, u) + wofs);
            #pragma unroll
            for (int bi = 0; bi < 4; ++bi) {
                float4 hv = h0r[bi][u];
                dot4(wa0, hv, acc0[0][bi]);
                dot4(wa1, hv, acc0[1][bi]);
                dot4(wb0, hv, acc1[0][bi]);
                dot4(wb1, hv, acc1[1][bi]);
            }
        }
        // 3. h1-pass: Whh1 -> acc1
        if (hasH1) {
            #pragma unroll
            for (int u = 0; u < 4; ++u) {
                float4 wc0 = *(const float4*)(lds + WBLK(2, 0, u) + wofs);
                float4 wc1 = *(const float4*)(lds + WBLK(2, 1, u) + wofs);
                #pragma unroll
                for (int bi = 0; bi < 4; ++bi) {
                    float4 hv = h1r[bi][u];
                    dot4(wc0, hv, acc1[0][bi]);
                    dot4(wc1, hv, acc1[1][bi]);
                }
            }
        }

        // 4. reduce over ks: 4-way in-wave, then 8 waves via LDS scratch
        #pragma unroll
        for (int jj = 0; jj < 2; ++jj)
            #pragma unroll
            for (int bi = 0; bi < 4; ++bi) {
                acc0[jj][bi] += __shfl_xor(acc0[jj][bi], 16);
                acc0[jj][bi] += __shfl_xor(acc0[jj][bi], 32);
                acc1[jj][bi] += __shfl_xor(acc1[jj][bi], 16);
                acc1[jj][bi] += __shfl_xor(acc1[jj][bi], 32);
            }
        if (lane < 16) {   // lane = bb*8+jp holds the 4-way sums
            #pragma unroll
            for (int jj = 0; jj < 2; ++jj)
                #pragma unroll
                for (int bi = 0; bi < 4; ++bi) {
                    lds[SCR + (wv * 16 + jj * 4 + bi) * SCRS + lane]     = acc0[jj][bi];
                    lds[SCR + (wv * 16 + 8 + jj * 4 + bi) * SCRS + lane] = acc1[jj][bi];
                }
        }
        __syncthreads();                                   // S2

        // 5. tail: 8-way sum, + z0 + bias, tanh, LLC store
        if (tid < 256) {
            const int l    = tid >> 7;
            const int jloc = tid & 15;                 // j = jg0 + jloc (= jp*2+jj)
            const int blo  = (tid >> 4) & 7;           // b = bg0 + blo (= bb*4+bi)
            const int a    = l * 8 + (jloc & 1) * 4 + (blo & 3);
            const int ll   = (jloc >> 1) + 8 * (blo >> 2);
            float s = 0.f;
            #pragma unroll
            for (int wq = 0; wq < 8; ++wq)
                s += lds[SCR + (wq * 16 + a) * SCRS + ll];
            float val = tanhf(s + bias + (l ? 0.f : z0cur));
            if (l == 0) {
                if (doL0) sys_st(h0buf + (size_t)cur * (BATCH * HH)
                                 + (size_t)(bg0 + blo) * HH + jg0 + jloc, val);
            } else {
                if (doL1) sys_st(out + ((size_t)(p - 1) * BATCH + bg0 + blo) * HH + jg0 + jloc, val);
            }
        }
        z0cur = z0n;
        wait_vm0();
        __syncthreads();                                   // S3: all stores drained

        // 6. group barrier: relaxed RMW arrival + relaxed poll at the LLC
        //    (hardware-proven R2/R3/R6; watchdog bounds any stall)
        if (tid == 0) {
            __hip_atomic_fetch_add(mycnt, 1u, __ATOMIC_RELAXED, __HIP_MEMORY_SCOPE_SYSTEM);
            target += WPG;
            if (!dead) {
                unsigned spins = 0;
                while (__hip_atomic_load(mycnt, __ATOMIC_RELAXED, __HIP_MEMORY_SCOPE_SYSTEM) < target) {
                    __builtin_amdgcn_s_sleep(2);
                    if (++spins > (1u << 21)) { dead = true; break; }
                }
            }
            asm volatile("" ::: "memory");
        } else {
            target += WPG;
        }
        __syncthreads();                                   // S4
    }
}

extern "C" void kernel_launch(void* const* d_in, const int* in_sizes, int n_in,
                              void* d_out, int out_size, void* d_ws, size_t ws_size,
                              hipStream_t stream) {
    (void)in_sizes; (void)n_in; (void)out_size; (void)ws_size;
    const float* Xt   = (const float*)d_in[0];
    const float* Wih0 = (const float*)d_in[1];
    const float* bih0 = (const float*)d_in[2];
    const float* Whh0 = (const float*)d_in[3];
    const float* bhh0 = (const float*)d_in[4];
    const float* Wih1 = (const float*)d_in[5];
    const float* bih1 = (const float*)d_in[6];
    const float* Whh1 = (const float*)d_in[7];
    const float* bhh1 = (const float*)d_in[8];
    float*    out   = (float*)d_out;
    float*    h0buf = (float*)d_ws;                          // 2*64*512 floats
    unsigned* cnt   = (unsigned*)((char*)d_ws + 2 * BATCH * HH * 4);  // 8 counters, 256B stride

    hipFuncSetAttribute((const void*)elman_persistent,
                        hipFuncAttributeMaxDynamicSharedMemorySize, LDS_BYTES);
    hipMemsetAsync(d_ws, 0, 2 * BATCH * HH * 4 + NG * 256, stream);

    // 1) Z0 = Xt@Wih0^T + bih0 -> out
    z0_gemm<<<dim3((TT * BATCH / 64) * (HH / 64)), dim3(256), 0, stream>>>(
        Xt, Wih0, bih0, out);

    // 2) persistent recurrence (3 matmuls/phase, activations direct from LLC)
    elman_persistent<<<dim3(NG * WPG), dim3(NTH), LDS_BYTES, stream>>>(
        Whh0, bhh0, Wih1, bih1, Whh1, bhh1, out, h0buf, cnt);
}